// Round 18
// baseline (389.549 us; speedup 1.0000x reference)
//
#include <hip/hip_runtime.h>
#include <math.h>

// Problem geometry (fixed by the reference):
//   preds   : (2, 2, 128, 128, 128) float32
//   targets : (2, 1, 128, 128, 128) int32
//   output  : scalar float32 = mean over (2,128,128,128) of
//             0.5*ce*(1 + 0.5*m_neg + 0.5*m_pos)
#define VOL   (128 * 128 * 128)   // 2,097,152 voxels per volume
#define NB    2                   // batch
#define TOTAL (NB * VOL)          // 4,194,304

#define INVP   0x7FFFFFFFu        // background sentinel in global parent arrays
#define FLAGB  0x80000000u        // "component has an error voxel" bit (root entry)
#define IDXM   0x7FFFFFFFu        // mask off the flag bit
#define LINV   0xFFFFFFFFu        // background sentinel in LDS parent arrays

// 16x16x16 tiles: 8x8x8 tiles per volume. Faces between tiles:
// per volume 3 dirs x 7x8x8 = 1344; two volumes.
#define TPV            (8 * 8 * 8)             // tiles per volume: 512
#define FACES_PER_DIR  (7 * 8 * 8)             // 448
#define FACES_PER_VOL  (3 * FACES_PER_DIR)     // 1344
#define NFACES         (NB * FACES_PER_VOL)    // 2688

// ---------------- global union-find (atomicMin-monotone, deterministic) ----
__device__ __forceinline__ unsigned find_root(unsigned* P, unsigned i) {
    while (true) {
        unsigned p = P[i] & IDXM;
        if (p == i) return i;
        unsigned gp = P[p] & IDXM;
        if (gp != p) atomicMin(&P[i], gp);   // path-halving, never raises a ptr
        i = gp;
    }
}

// read-only find: used where concurrent flag bits may live on chain nodes
// (a halving atomicMin would numerically clear bit31 — must not write).
__device__ __forceinline__ unsigned find_root_ro(const unsigned* P, unsigned i) {
    while (true) {
        unsigned p = P[i] & IDXM;
        if (p == i) return i;
        i = p;
    }
}

__device__ __forceinline__ void unite(unsigned* P, unsigned a, unsigned b) {
    a = find_root(P, a);
    b = find_root(P, b);
    while (a != b) {
        if (b > a) { unsigned t = a; a = b; b = t; }   // link a (larger) under b
        unsigned old = atomicMin(&P[a], b);
        if (old == a) return;
        a = find_root(P, old & IDXM);
        b = find_root(P, b);
    }
}

// ---------------- LDS union-find (same invariants, tile-local ids) ---------
__device__ __forceinline__ unsigned lfind(unsigned* L, unsigned i) {
    while (true) {
        unsigned p = L[i];
        if (p == i) return i;
        unsigned gp = L[p];
        if (gp != p) atomicMin(&L[i], gp);
        i = gp;
    }
}

__device__ __forceinline__ void lunite(unsigned* L, unsigned a, unsigned b) {
    a = lfind(L, a);
    b = lfind(L, b);
    while (a != b) {
        if (b > a) { unsigned t = a; a = b; b = t; }
        unsigned old = atomicMin(&L[a], b);
        if (old == a) return;
        a = lfind(L, old);
        b = lfind(L, b);
    }
}

// Wave-dedup helper: one leader lane per distinct key among `need` lanes.
// Leaders return true AFTER the peel loop so their (latency-heavy) work runs
// concurrently across lanes instead of serialized inside the loop.
__device__ __forceinline__ bool dedup_leader(bool need, unsigned key) {
    unsigned lane = threadIdx.x & 63;
    bool leader = false;
    unsigned long long rem = __ballot(need);
    while (rem) {
        int src = __ffsll(rem) - 1;
        unsigned s = __shfl(key, src);
        if (need && key == s) {
            leader = (lane == (unsigned)src);
            need = false;
        }
        rem = __ballot(need);
    }
    return leader;
}

// ---------------- kernels ----------------

// Phase 1: fused init + tile-local CCL. One block = one 16x16x16 tile (4096
// voxels, 256 threads x 16). All intra-tile connectivity resolved via LDS
// union-find (32 KB); each voxel's global parent is written as the global id
// of its tile-local root (plain store — tile owns these entries here).
__global__ void k_local(const float* __restrict__ preds,
                        const int* __restrict__ tgt,
                        unsigned* __restrict__ Pp,
                        unsigned* __restrict__ Pt) {
    __shared__ unsigned lpp[4096], lpt[4096];
    unsigned tile = blockIdx.x;                  // 0..1023
    unsigned b  = tile >> 9;                     // 512 tiles per volume
    unsigned tz = (tile >> 6) & 7, ty = (tile >> 3) & 7, tx = tile & 7;
    unsigned base_v = tz * (16 * 16384) + ty * (16 * 128) + tx * 16;
    unsigned base_g = b * VOL + base_v;

    // init: load masks, seed LDS parents
    for (int l = threadIdx.x; l < 4096; l += 256) {
        unsigned lx = l & 15, ly = (l >> 4) & 15, lz = l >> 8;
        unsigned voli = base_v + lz * 16384 + ly * 128 + lx;
        float p1 = preds[(size_t)(b * 2 + 1) * VOL + voli];   // channel-1 logit
        int   t  = tgt[b * VOL + voli];
        lpp[l] = (p1 > 0.0f) ? (unsigned)l : LINV;
        lpt[l] = (t > 0)     ? (unsigned)l : LINV;
    }
    __syncthreads();

    // local unites over the 3 forward links (bg entries never participate:
    // fg-ness of an entry is stable — fg stays < 4096, bg stays LINV)
    for (int l = threadIdx.x; l < 4096; l += 256) {
        unsigned lx = l & 15, ly = (l >> 4) & 15, lz = l >> 8;
        if (lpp[l] != LINV) {
            if (lx < 15 && lpp[l + 1]   != LINV) lunite(lpp, l, l + 1);
            if (ly < 15 && lpp[l + 16]  != LINV) lunite(lpp, l, l + 16);
            if (lz < 15 && lpp[l + 256] != LINV) lunite(lpp, l, l + 256);
        }
        if (lpt[l] != LINV) {
            if (lx < 15 && lpt[l + 1]   != LINV) lunite(lpt, l, l + 1);
            if (ly < 15 && lpt[l + 16]  != LINV) lunite(lpt, l, l + 16);
            if (lz < 15 && lpt[l + 256] != LINV) lunite(lpt, l, l + 256);
        }
    }
    __syncthreads();

    // compress to tile root, write global parents (flat 1-hop trees)
    for (int l = threadIdx.x; l < 4096; l += 256) {
        unsigned lx = l & 15, ly = (l >> 4) & 15, lz = l >> 8;
        unsigned g = base_g + lz * 16384 + ly * 128 + lx;
        if (lpp[l] != LINV) {
            unsigned r = lfind(lpp, l);
            Pp[g] = base_g + (r >> 8) * 16384 + ((r >> 4) & 15) * 128 + (r & 15);
        } else Pp[g] = INVP;
        if (lpt[l] != LINV) {
            unsigned r = lfind(lpt, l);
            Pt[g] = base_g + (r >> 8) * 16384 + ((r >> 4) & 15) * 128 + (r & 15);
        } else Pt[g] = INVP;
    }
}

// Phase 2: face-centric boundary merge. One BLOCK per 16x16 tile face (256
// links). Stored parents are exact tile roots, so per-wave dedup of
// (leftParent, rightParent) pairs removes nearly all redundant unites.
__global__ void k_bmerge(unsigned* __restrict__ Pp, unsigned* __restrict__ Pt) {
    unsigned fid = blockIdx.x;
    unsigned vol = fid / FACES_PER_VOL;
    unsigned r   = fid % FACES_PER_VOL;
    unsigned dir = r / FACES_PER_DIR;
    unsigned fr  = r % FACES_PER_DIR;
    unsigned b0 = fr % 7;             // boundary index along dir (tile b0|b0+1)
    unsigned t1 = (fr / 7) % 8;       // tile coords in the other two axes
    unsigned t2 = fr / 56;
    unsigned u = threadIdx.x & 15, v = threadIdx.x >> 4;  // 16x16 face pos
    unsigned lane = threadIdx.x & 63;

    unsigned x, y, z, step;
    if (dir == 0)      { x = b0 * 16 + 15; y = t1 * 16 + u; z = t2 * 16 + v; step = 1; }
    else if (dir == 1) { y = b0 * 16 + 15; x = t1 * 16 + u; z = t2 * 16 + v; step = 128; }
    else               { z = b0 * 16 + 15; x = t1 * 16 + u; y = t2 * 16 + v; step = 16384; }
    unsigned g = vol * VOL + z * 16384 + y * 128 + x;

    for (int arr = 0; arr < 2; ++arr) {
        unsigned* P = arr ? Pt : Pp;
        unsigned a = P[g];                 // tile root (or INVP)
        unsigned bb = P[g + step];
        bool need = (a != INVP) && (bb != INVP);
        bool leader = false;
        unsigned long long rem = __ballot(need);
        while (rem) {
            int src = __ffsll(rem) - 1;
            unsigned sa = __shfl(a, src), sb = __shfl(bb, src);
            if (need && a == sa && bb == sb) {
                leader = ((int)lane == src);
                need = false;
            }
            rem = __ballot(need);
        }
        if (leader) unite(P, a, bb);
    }
}

// Phase 3a (flag-up): per voxel, if it is an error (fg && !other_fg), flag its
// GLOBAL root. Wave-dedup on the tile-root value; leaders find+flag
// concurrently. Path-halving in find_root is safe here: flags exist only on
// global roots, and halving never writes a root entry.
__global__ void k_flaga(unsigned* __restrict__ Pp, unsigned* __restrict__ Pt) {
    unsigned g = blockIdx.x * blockDim.x + threadIdx.x;
    if (g >= TOTAL) return;
    unsigned vp = Pp[g], vt = Pt[g];
    bool pf = (vp != INVP), tf = (vt != INVP);

    bool lp = dedup_leader(pf && !tf, vp & IDXM);   // m_pos: pred comp w/ err
    if (lp) {
        unsigned root = find_root(Pp, vp & IDXM);
        if (!(Pp[root] & FLAGB)) atomicOr(&Pp[root], FLAGB);
    }
    bool lt = dedup_leader(tf && !pf, vt & IDXM);   // m_neg: tgt comp w/ err
    if (lt) {
        unsigned root = find_root(Pt, vt & IDXM);
        if (!(Pt[root] & FLAGB)) atomicOr(&Pt[root], FLAGB);
    }
}

// Phase 3b (pull-down): copy each flagged component's flag from its global
// root onto every DIRECT-parent tile root (exactly the entries k_loss reads).
// Must use the read-only find: tile roots being flagged concurrently sit on
// other threads' chains, and a halving atomicMin would clear bit31.
__global__ void k_flagb(unsigned* __restrict__ Pp, unsigned* __restrict__ Pt) {
    unsigned g = blockIdx.x * blockDim.x + threadIdx.x;
    if (g >= TOTAL) return;
    unsigned vp = Pp[g], vt = Pt[g];

    bool lp = dedup_leader(vp != INVP, vp & IDXM);
    if (lp) {
        unsigned tr = vp & IDXM;
        unsigned root = find_root_ro(Pp, tr);
        if ((Pp[root] & FLAGB) && !(Pp[tr] & FLAGB)) atomicOr(&Pp[tr], FLAGB);
    }
    bool lt = dedup_leader(vt != INVP, vt & IDXM);
    if (lt) {
        unsigned tr = vt & IDXM;
        unsigned root = find_root_ro(Pt, tr);
        if ((Pt[root] & FLAGB) && !(Pt[tr] & FLAGB)) atomicOr(&Pt[tr], FLAGB);
    }
}

__global__ void k_loss(const float* __restrict__ preds,
                       const int* __restrict__ tgt,
                       const unsigned* __restrict__ Pp,
                       const unsigned* __restrict__ Pt,
                       float* __restrict__ partial) {
    float acc = 0.0f;
    for (unsigned g = blockIdx.x * blockDim.x + threadIdx.x; g < TOTAL;
         g += gridDim.x * blockDim.x) {
        unsigned b = g >> 21;
        unsigned i = g & (VOL - 1);
        float p0 = preds[((size_t)(b * 2 + 0)) * VOL + i];
        float p1 = preds[((size_t)(b * 2 + 1)) * VOL + i];
        int   t  = tgt[g];
        // 2-class CE: -log_softmax(preds)[t] == softplus(p_other - p_t)
        float z  = (t > 0) ? (p0 - p1) : (p1 - p0);
        float ce = (z > 0.0f) ? (z + log1pf(expf(-z))) : log1pf(expf(z));

        unsigned vp = Pp[g], vt = Pt[g];
        float crit = 0.0f;
        if (vt != INVP) {                        // direct parent = tile root
            unsigned r = vt & IDXM;
            if (Pt[r] & FLAGB) crit += 0.5f;     // BETA * m_neg
        }
        if (vp != INVP) {
            unsigned r = vp & IDXM;
            if (Pp[r] & FLAGB) crit += 0.5f;     // (1-BETA) * m_pos
        }
        acc += 0.5f * ce * (1.0f + crit);        // (1-A)*ce + A*crit*ce, A=0.5
    }
    for (int off = 32; off > 0; off >>= 1) acc += __shfl_down(acc, off);
    __shared__ float s[4];
    int wid = threadIdx.x >> 6, lane = threadIdx.x & 63;
    if (lane == 0) s[wid] = acc;
    __syncthreads();
    if (threadIdx.x == 0) {
        float tacc = 0.0f;
        for (int w = 0; w < (int)(blockDim.x >> 6); ++w) tacc += s[w];
        partial[blockIdx.x] = tacc;
    }
}

__global__ void k_final(const float* __restrict__ partial, int n,
                        float* __restrict__ out) {
    double acc = 0.0;
    for (int i = threadIdx.x; i < n; i += blockDim.x) acc += (double)partial[i];
    for (int off = 32; off > 0; off >>= 1) acc += __shfl_down(acc, off);
    __shared__ double s[4];
    int wid = threadIdx.x >> 6, lane = threadIdx.x & 63;
    if (lane == 0) s[wid] = acc;
    __syncthreads();
    if (threadIdx.x == 0) {
        double t = 0.0;
        for (int w = 0; w < (int)(blockDim.x >> 6); ++w) t += s[w];
        out[0] = (float)(t / (double)TOTAL);
    }
}

// ---------------- launch ----------------

extern "C" void kernel_launch(void* const* d_in, const int* in_sizes, int n_in,
                              void* d_out, int out_size, void* d_ws, size_t ws_size,
                              hipStream_t stream) {
    const float* preds   = (const float*)d_in[0];   // (2,2,128,128,128) f32
    const int*   targets = (const int*)d_in[1];     // (2,1,128,128,128) i32
    float*       out     = (float*)d_out;           // scalar

    // workspace layout: Pp[TOTAL] u32 | Pt[TOTAL] u32 | partial[2048] f32
    unsigned* Pp = (unsigned*)d_ws;
    unsigned* Pt = Pp + TOTAL;
    float* partial = (float*)(Pt + TOTAL);

    const int T = 256;
    const int NTILE = NB * TPV;               // 1024 16x16x16 tiles
    k_local <<<NTILE, T, 0, stream>>>(preds, targets, Pp, Pt);
    k_bmerge<<<NFACES, T, 0, stream>>>(Pp, Pt);   // 1 block per 16x16 face
    k_flaga <<<TOTAL / T, T, 0, stream>>>(Pp, Pt);
    k_flagb <<<TOTAL / T, T, 0, stream>>>(Pp, Pt);

    const int RB = 2048;
    k_loss <<<RB, T, 0, stream>>>(preds, targets, Pp, Pt, partial);
    k_final<<<1, T, 0, stream>>>(partial, RB, out);
}